// Round 1
// baseline (1934.941 us; speedup 1.0000x reference)
//
#include <hip/hip_runtime.h>
#include <hip/hip_bf16.h>

// Sizes (compile-time constants for this problem)
#define P_DIM 128
#define G_DIM 1024
#define C_DIM 512
#define M_DIM (P_DIM * G_DIM)       // 131072
#define NUM_IDS 64
#define RESULT_ELEMS (M_DIM * 2)    // 262144
#define LABEL_ELEMS  (M_DIM)        // 131072

constexpr int BM = 128, BN = 128, BK = 16;

// ---------------------------------------------------------------------------
// Prep: fold BN into alpha/beta, compute per-class 1/(n_k+1)
// ---------------------------------------------------------------------------
__global__ void prep_kernel(const float* __restrict__ b1, const float* __restrict__ g1,
                            const float* __restrict__ be1, const float* __restrict__ rm1,
                            const float* __restrict__ rv1,
                            const float* __restrict__ b2, const float* __restrict__ g2,
                            const float* __restrict__ be2, const float* __restrict__ rm2,
                            const float* __restrict__ rv2,
                            const int* __restrict__ y_g,
                            float* __restrict__ alpha1, float* __restrict__ beta1,
                            float* __restrict__ alpha2, float* __restrict__ beta2,
                            float* __restrict__ inv)
{
    __shared__ int cnt[NUM_IDS];
    int tid = threadIdx.x;  // 512 threads
    if (tid < NUM_IDS) cnt[tid] = 0;
    __syncthreads();
    if (tid < C_DIM) {
        float s1 = g1[tid] * rsqrtf(rv1[tid] + 1e-5f);
        alpha1[tid] = s1;
        beta1[tid]  = (b1[tid] - rm1[tid]) * s1 + be1[tid];
        float s2 = g2[tid] * rsqrtf(rv2[tid] + 1e-5f);
        alpha2[tid] = s2;
        beta2[tid]  = (b2[tid] - rm2[tid]) * s2 + be2[tid];
    }
    for (int h = tid; h < G_DIM; h += 512) atomicAdd(&cnt[y_g[h]], 1);
    __syncthreads();
    if (tid < NUM_IDS) inv[tid] = 1.0f / (float)(cnt[tid] + 1);
}

// ---------------------------------------------------------------------------
// Tiled f32 GEMM  Z = A[M x 512] * B[512 x 512]  with fused epilogue.
// MODE 1: Cout = lrelu(Z*alpha + beta)                       (writes h1)
// MODE 2: h2 = lrelu(Z*alpha+beta); u[r,0..1] += h2 @ Wc     (atomics, no h2 store)
// ---------------------------------------------------------------------------
template <int MODE>
__global__ __launch_bounds__(256)
void gemm_bn_lrelu(const float* __restrict__ A, const float* __restrict__ B,
                   const float* __restrict__ alpha, const float* __restrict__ beta,
                   float* __restrict__ Cout,
                   const float* __restrict__ Wc, float* __restrict__ u)
{
    __shared__ float As[BK][BM];
    __shared__ float Bs[BK][BN];

    const int tid = threadIdx.x;
    const int m0 = blockIdx.y * BM;
    const int n0 = blockIdx.x * BN;
    const int ty = tid >> 4;   // 0..15 -> row group
    const int tx = tid & 15;   // 0..15 -> col group

    float acc[8][8] = {};

    for (int k0 = 0; k0 < C_DIM; k0 += BK) {
        // Load A tile (BM x BK), store transposed As[k][m]
#pragma unroll
        for (int p = 0; p < 2; ++p) {
            int l4 = tid + p * 256;          // float4 index within 128x16 tile
            int m = l4 >> 2;                 // 0..127
            int k = (l4 & 3) * 4;            // 0,4,8,12
            float4 v = *(const float4*)(A + (size_t)(m0 + m) * C_DIM + k0 + k);
            As[k + 0][m] = v.x; As[k + 1][m] = v.y;
            As[k + 2][m] = v.z; As[k + 3][m] = v.w;
        }
        // Load B tile (BK x BN) directly
#pragma unroll
        for (int p = 0; p < 2; ++p) {
            int l4 = tid + p * 256;          // float4 index within 16x128 tile
            int k = l4 >> 5;                 // 0..15
            int n = (l4 & 31) * 4;           // 0..124
            *(float4*)(&Bs[k][n]) = *(const float4*)(B + (size_t)(k0 + k) * C_DIM + n0 + n);
        }
        __syncthreads();
#pragma unroll
        for (int kk = 0; kk < BK; ++kk) {
            float a[8], b[8];
            *(float4*)(a)     = *(const float4*)(&As[kk][ty * 8]);
            *(float4*)(a + 4) = *(const float4*)(&As[kk][ty * 8 + 4]);
            *(float4*)(b)     = *(const float4*)(&Bs[kk][tx * 8]);
            *(float4*)(b + 4) = *(const float4*)(&Bs[kk][tx * 8 + 4]);
#pragma unroll
            for (int i = 0; i < 8; ++i)
#pragma unroll
                for (int j = 0; j < 8; ++j)
                    acc[i][j] = fmaf(a[i], b[j], acc[i][j]);
        }
        __syncthreads();
    }

    float al[8], bt[8];
#pragma unroll
    for (int j = 0; j < 8; ++j) {
        int c = n0 + tx * 8 + j;
        al[j] = alpha[c];
        bt[j] = beta[c];
    }

    if (MODE == 1) {
#pragma unroll
        for (int i = 0; i < 8; ++i) {
            int gr = m0 + ty * 8 + i;
            float o[8];
#pragma unroll
            for (int j = 0; j < 8; ++j) {
                float v = fmaf(acc[i][j], al[j], bt[j]);
                o[j] = v >= 0.f ? v : 0.1f * v;
            }
            float* dst = Cout + (size_t)gr * C_DIM + n0 + tx * 8;
            *(float4*)(dst)     = *(float4*)(o);
            *(float4*)(dst + 4) = *(float4*)(o + 4);
        }
    } else {
        float wc0[8], wc1[8];
#pragma unroll
        for (int j = 0; j < 8; ++j) {
            int c = n0 + tx * 8 + j;
            wc0[j] = Wc[c * 2 + 0];
            wc1[j] = Wc[c * 2 + 1];
        }
#pragma unroll
        for (int i = 0; i < 8; ++i) {
            int gr = m0 + ty * 8 + i;
            float pu0 = 0.f, pu1 = 0.f;
#pragma unroll
            for (int j = 0; j < 8; ++j) {
                float v = fmaf(acc[i][j], al[j], bt[j]);
                v = v >= 0.f ? v : 0.1f * v;
                pu0 = fmaf(v, wc0[j], pu0);
                pu1 = fmaf(v, wc1[j], pu1);
            }
            // reduce over tx (low 4 lane bits) — stays inside the wave
#pragma unroll
            for (int s = 1; s < 16; s <<= 1) {
                pu0 += __shfl_xor(pu0, s, 64);
                pu1 += __shfl_xor(pu1, s, 64);
            }
            if (tx == 0) {
                atomicAdd(&u[(size_t)gr * 2 + 0], pu0);
                atomicAdd(&u[(size_t)gr * 2 + 1], pu1);
            }
        }
    }
}

// ---------------------------------------------------------------------------
// Finalize: per p, class-sum u over g, then result = (su + u)*inv + bc
// ---------------------------------------------------------------------------
__global__ void finalize_kernel(const float* __restrict__ u, const int* __restrict__ y_g,
                                const float* __restrict__ inv, const float* __restrict__ bc,
                                float* __restrict__ out)
{
    int p = blockIdx.x;
    int tid = threadIdx.x;  // 256
    __shared__ float su[NUM_IDS][2];
    if (tid < NUM_IDS * 2) su[tid >> 1][tid & 1] = 0.f;
    __syncthreads();
    for (int h = tid; h < G_DIM; h += 256) {
        int k = y_g[h];
        const float* up = u + ((size_t)p * G_DIM + h) * 2;
        atomicAdd(&su[k][0], up[0]);
        atomicAdd(&su[k][1], up[1]);
    }
    __syncthreads();
    float bc0 = bc[0], bc1 = bc[1];
    for (int h = tid; h < G_DIM; h += 256) {
        int k = y_g[h];
        float iv = inv[k];
        size_t r = (size_t)p * G_DIM + h;
        out[r * 2 + 0] = (su[k][0] + u[r * 2 + 0]) * iv + bc0;
        out[r * 2 + 1] = (su[k][1] + u[r * 2 + 1]) * iv + bc1;
    }
}

// ---------------------------------------------------------------------------
// Label: (y_p[p] == y_g[g]); mode 1 -> float, mode 2 -> int64
// ---------------------------------------------------------------------------
__global__ void label_kernel(const int* __restrict__ y_p, const int* __restrict__ y_g,
                             float* __restrict__ outF, long long* __restrict__ outL, int mode)
{
    int i = blockIdx.x * 256 + threadIdx.x;
    if (i >= LABEL_ELEMS) return;
    int p = i >> 10;
    int g = i & 1023;
    long long lab = (y_p[p] == y_g[g]) ? 1 : 0;
    if (mode == 1) outF[i] = (float)lab;
    else           outL[i] = lab;
}

// ---------------------------------------------------------------------------
extern "C" void kernel_launch(void* const* d_in, const int* in_sizes, int n_in,
                              void* d_out, int out_size, void* d_ws, size_t ws_size,
                              hipStream_t stream) {
    const float* d   = (const float*)d_in[0];
    const int*   y_p = (const int*)d_in[1];
    const int*   y_g = (const int*)d_in[2];
    const float* W1  = (const float*)d_in[3];
    const float* b1  = (const float*)d_in[4];
    const float* g1  = (const float*)d_in[5];
    const float* be1 = (const float*)d_in[6];
    const float* rm1 = (const float*)d_in[7];
    const float* rv1 = (const float*)d_in[8];
    const float* W2  = (const float*)d_in[9];
    const float* b2  = (const float*)d_in[10];
    const float* g2  = (const float*)d_in[11];
    const float* be2 = (const float*)d_in[12];
    const float* rm2 = (const float*)d_in[13];
    const float* rv2 = (const float*)d_in[14];
    const float* Wc  = (const float*)d_in[15];
    const float* bc  = (const float*)d_in[16];

    // ws layout (floats)
    float* ws = (float*)d_ws;
    float* h1     = ws;                              // 131072*512
    float* u      = ws + (size_t)M_DIM * C_DIM;      // 131072*2
    float* alpha1 = u + RESULT_ELEMS;                // 512
    float* beta1  = alpha1 + C_DIM;
    float* alpha2 = beta1 + C_DIM;
    float* beta2  = alpha2 + C_DIM;
    float* inv    = beta2 + C_DIM;                   // 64

    hipMemsetAsync(u, 0, RESULT_ELEMS * sizeof(float), stream);

    prep_kernel<<<1, 512, 0, stream>>>(b1, g1, be1, rm1, rv1, b2, g2, be2, rm2, rv2,
                                       y_g, alpha1, beta1, alpha2, beta2, inv);

    dim3 grid(C_DIM / BN, M_DIM / BM);  // (4, 1024)
    gemm_bn_lrelu<1><<<grid, 256, 0, stream>>>(d,  W1, alpha1, beta1, h1, nullptr, nullptr);
    gemm_bn_lrelu<2><<<grid, 256, 0, stream>>>(h1, W2, alpha2, beta2, nullptr, Wc, u);

    float* outF = (float*)d_out;
    finalize_kernel<<<P_DIM, 256, 0, stream>>>(u, y_g, inv, bc, outF);

    // label output placement depends on how the harness concatenates int64
    int mode = 0;
    if (out_size >= RESULT_ELEMS + 2 * LABEL_ELEMS) mode = 2;        // int64 (8B) slots
    else if (out_size >= RESULT_ELEMS + LABEL_ELEMS) mode = 1;       // cast to float
    if (mode)
        label_kernel<<<(LABEL_ELEMS + 255) / 256, 256, 0, stream>>>(
            y_p, y_g, outF + RESULT_ELEMS, (long long*)(outF + RESULT_ELEMS), mode);
}

// Round 2
// 731.281 us; speedup vs baseline: 2.6460x; 2.6460x over previous
//
#include <hip/hip_runtime.h>
#include <hip/hip_bf16.h>

#define P_DIM 128
#define G_DIM 1024
#define C_DIM 512
#define M_DIM (P_DIM * G_DIM)       // 131072
#define NUM_IDS 64
#define RESULT_ELEMS (M_DIM * 2)    // 262144
#define LABEL_ELEMS  (M_DIM)        // 131072

typedef __bf16 bf16;
typedef __bf16 bf16x8 __attribute__((ext_vector_type(8)));
typedef float f32x4 __attribute__((ext_vector_type(4)));

constexpr int BM = 64;        // rows per block
constexpr int BK = 32;        // K-step (one MFMA K)
constexpr int BNC = 128;      // output-column chunk
constexpr int APITCH = 40;    // As pitch (bf16 elems), 80 B: 16B-aligned rows, 2-way banks
constexpr int BPITCH = 40;    // Bs pitch
constexpr int HPITCH = 520;   // h1s pitch, 1040 B: 16B-aligned, spreads banks

// ---------------------------------------------------------------------------
// Prep: fold BN into alpha/beta, per-class 1/(n_k+1)
// ---------------------------------------------------------------------------
__global__ void prep_kernel(const float* __restrict__ b1, const float* __restrict__ g1,
                            const float* __restrict__ be1, const float* __restrict__ rm1,
                            const float* __restrict__ rv1,
                            const float* __restrict__ b2, const float* __restrict__ g2,
                            const float* __restrict__ be2, const float* __restrict__ rm2,
                            const float* __restrict__ rv2,
                            const int* __restrict__ y_g,
                            float* __restrict__ alpha1, float* __restrict__ beta1,
                            float* __restrict__ alpha2, float* __restrict__ beta2,
                            float* __restrict__ inv)
{
    __shared__ int cnt[NUM_IDS];
    int tid = threadIdx.x;  // 512 threads
    if (tid < NUM_IDS) cnt[tid] = 0;
    __syncthreads();
    if (tid < C_DIM) {
        float s1 = g1[tid] * rsqrtf(rv1[tid] + 1e-5f);
        alpha1[tid] = s1;
        beta1[tid]  = (b1[tid] - rm1[tid]) * s1 + be1[tid];
        float s2 = g2[tid] * rsqrtf(rv2[tid] + 1e-5f);
        alpha2[tid] = s2;
        beta2[tid]  = (b2[tid] - rm2[tid]) * s2 + be2[tid];
    }
    for (int h = tid; h < G_DIM; h += 512) atomicAdd(&cnt[y_g[h]], 1);
    __syncthreads();
    if (tid < NUM_IDS) inv[tid] = 1.0f / (float)(cnt[tid] + 1);
}

// ---------------------------------------------------------------------------
// WT[n][k] = W[k][n] * s[n], f32 -> bf16  (K-contiguous for MFMA operands)
// ---------------------------------------------------------------------------
__global__ __launch_bounds__(256) void transpose_scale(
    const float* __restrict__ W, const float* __restrict__ s, bf16* __restrict__ WT)
{
    __shared__ float tile[64][65];
    const int k0 = blockIdx.x * 64, n0 = blockIdx.y * 64;
    const int t = threadIdx.x;
    const int c = t & 63, r4 = t >> 6;
#pragma unroll
    for (int it = 0; it < 16; ++it) {
        int k = r4 + it * 4;
        tile[k][c] = W[(size_t)(k0 + k) * C_DIM + n0 + c];  // coalesced read
    }
    __syncthreads();
#pragma unroll
    for (int it = 0; it < 16; ++it) {
        int n = r4 + it * 4;
        float sv = s[n0 + n];
        WT[(size_t)(n0 + n) * C_DIM + k0 + c] = (bf16)(tile[c][n] * sv);  // coalesced write
    }
}

// ---------------------------------------------------------------------------
// Fused: h1 = lrelu(d@W1T'+beta1) (kept in LDS, bf16)
//        h2 = lrelu(h1@W2T'+beta2); u[row,0:2] = h2 @ Wc   (h1,h2 never hit HBM)
// 256 threads = 4 waves (2M x 2N), wave tile 32x64, frags 2(M) x 4(N), MFMA 16x16x32.
// ---------------------------------------------------------------------------
__global__ __launch_bounds__(256, 2) void fused_gnn(
    const float* __restrict__ d,
    const bf16* __restrict__ W1T, const float* __restrict__ beta1,
    const bf16* __restrict__ W2T, const float* __restrict__ beta2,
    const float* __restrict__ Wc, float* __restrict__ u)
{
    __shared__ union {
        bf16  As[BM][APITCH];     // stage-1 A staging
        float ur[BM][2];          // final u reduction (stage 2 only)
    } sA;
    __shared__ bf16 Bs[BNC][BPITCH];
    __shared__ bf16 h1s[BM][HPITCH];
    // total LDS = 5120 + 10240 + 66560 = 81920 B -> 2 blocks/CU

    const int tid = threadIdx.x;
    const int ln  = tid & 63;
    const int wid = tid >> 6;
    const int wm  = wid & 1;
    const int wn  = wid >> 1;
    const int l15 = ln & 15;
    const int lg  = ln >> 4;
    const size_t gm0 = (size_t)blockIdx.x * BM;

    // staging assignments
    const int ar = tid >> 2;           // A row 0..63
    const int aq = (tid & 3) * 8;      // A k-offset {0,8,16,24}
    const int bn = tid >> 1;           // B row 0..127
    const int bq = (tid & 1) * 16;     // B k-offset {0,16}

    // ================= Stage 1 =================
    for (int chunk = 0; chunk < 4; ++chunk) {
        const int n0 = chunk * BNC;
        f32x4 acc[2][4];
#pragma unroll
        for (int fm = 0; fm < 2; ++fm)
#pragma unroll
            for (int fn = 0; fn < 4; ++fn)
                acc[fm][fn] = (f32x4){0.f, 0.f, 0.f, 0.f};

        // prefetch k0 = 0
        float4 pa0 = *(const float4*)(d + (gm0 + ar) * C_DIM + aq);
        float4 pa1 = *(const float4*)(d + (gm0 + ar) * C_DIM + aq + 4);
        float4 pb0 = *(const float4*)(W1T + (size_t)(n0 + bn) * C_DIM + bq);
        float4 pb1 = *(const float4*)(W1T + (size_t)(n0 + bn) * C_DIM + bq + 8);

        for (int k0 = 0; k0 < C_DIM; k0 += BK) {
            __syncthreads();                       // prior tile's reads done
            {
                bf16x8 av;
                av[0]=(bf16)pa0.x; av[1]=(bf16)pa0.y; av[2]=(bf16)pa0.z; av[3]=(bf16)pa0.w;
                av[4]=(bf16)pa1.x; av[5]=(bf16)pa1.y; av[6]=(bf16)pa1.z; av[7]=(bf16)pa1.w;
                *(bf16x8*)&sA.As[ar][aq] = av;
                *(float4*)&Bs[bn][bq]     = pb0;
                *(float4*)&Bs[bn][bq + 8] = pb1;
            }
            __syncthreads();
            if (k0 + BK < C_DIM) {                 // prefetch next (hides under MFMA)
                pa0 = *(const float4*)(d + (gm0 + ar) * C_DIM + (k0 + BK) + aq);
                pa1 = *(const float4*)(d + (gm0 + ar) * C_DIM + (k0 + BK) + aq + 4);
                pb0 = *(const float4*)(W1T + (size_t)(n0 + bn) * C_DIM + (k0 + BK) + bq);
                pb1 = *(const float4*)(W1T + (size_t)(n0 + bn) * C_DIM + (k0 + BK) + bq + 8);
            }
            bf16x8 af[2], bfr[4];
#pragma unroll
            for (int fm = 0; fm < 2; ++fm)
                af[fm] = *(const bf16x8*)&sA.As[wm * 32 + fm * 16 + l15][lg * 8];
#pragma unroll
            for (int fn = 0; fn < 4; ++fn)
                bfr[fn] = *(const bf16x8*)&Bs[wn * 64 + fn * 16 + l15][lg * 8];
#pragma unroll
            for (int fm = 0; fm < 2; ++fm)
#pragma unroll
                for (int fn = 0; fn < 4; ++fn)
                    acc[fm][fn] = __builtin_amdgcn_mfma_f32_16x16x32_bf16(
                        af[fm], bfr[fn], acc[fm][fn], 0, 0, 0);
        }
        // epilogue: bias + lrelu -> h1s (each wave writes disjoint rows/cols)
#pragma unroll
        for (int fn = 0; fn < 4; ++fn) {
            int c = n0 + wn * 64 + fn * 16 + l15;
            float be = beta1[c];
#pragma unroll
            for (int fm = 0; fm < 2; ++fm) {
                int mrow = wm * 32 + fm * 16 + lg * 4;
#pragma unroll
                for (int j = 0; j < 4; ++j) {
                    float v = acc[fm][fn][j] + be;
                    v = v >= 0.f ? v : 0.1f * v;
                    h1s[mrow + j][c] = (bf16)v;
                }
            }
        }
    }

    __syncthreads();                 // h1s complete; As no longer read
    if (tid < BM * 2) sA.ur[tid >> 1][tid & 1] = 0.f;   // zero u reduction buf

    // ================= Stage 2 =================
    float pu0[2][4] = {}, pu1[2][4] = {};
    for (int chunk = 0; chunk < 4; ++chunk) {
        const int n0 = chunk * BNC;
        f32x4 acc[2][4];
#pragma unroll
        for (int fm = 0; fm < 2; ++fm)
#pragma unroll
            for (int fn = 0; fn < 4; ++fn)
                acc[fm][fn] = (f32x4){0.f, 0.f, 0.f, 0.f};

        float4 pb0 = *(const float4*)(W2T + (size_t)(n0 + bn) * C_DIM + bq);
        float4 pb1 = *(const float4*)(W2T + (size_t)(n0 + bn) * C_DIM + bq + 8);

        for (int k0 = 0; k0 < C_DIM; k0 += BK) {
            __syncthreads();
            *(float4*)&Bs[bn][bq]     = pb0;
            *(float4*)&Bs[bn][bq + 8] = pb1;
            __syncthreads();
            if (k0 + BK < C_DIM) {
                pb0 = *(const float4*)(W2T + (size_t)(n0 + bn) * C_DIM + (k0 + BK) + bq);
                pb1 = *(const float4*)(W2T + (size_t)(n0 + bn) * C_DIM + (k0 + BK) + bq + 8);
            }
            bf16x8 af[2], bfr[4];
#pragma unroll
            for (int fm = 0; fm < 2; ++fm)
                af[fm] = *(const bf16x8*)&h1s[wm * 32 + fm * 16 + l15][k0 + lg * 8];
#pragma unroll
            for (int fn = 0; fn < 4; ++fn)
                bfr[fn] = *(const bf16x8*)&Bs[wn * 64 + fn * 16 + l15][lg * 8];
#pragma unroll
            for (int fm = 0; fm < 2; ++fm)
#pragma unroll
                for (int fn = 0; fn < 4; ++fn)
                    acc[fm][fn] = __builtin_amdgcn_mfma_f32_16x16x32_bf16(
                        af[fm], bfr[fn], acc[fm][fn], 0, 0, 0);
        }
        // epilogue: bias + lrelu, fold Wc into per-row partials
#pragma unroll
        for (int fn = 0; fn < 4; ++fn) {
            int c = n0 + wn * 64 + fn * 16 + l15;
            float be = beta2[c];
            float w0 = Wc[2 * c], w1 = Wc[2 * c + 1];
#pragma unroll
            for (int fm = 0; fm < 2; ++fm)
#pragma unroll
                for (int j = 0; j < 4; ++j) {
                    float v = acc[fm][fn][j] + be;
                    v = v >= 0.f ? v : 0.1f * v;
                    pu0[fm][j] = fmaf(v, w0, pu0[fm][j]);
                    pu1[fm][j] = fmaf(v, w1, pu1[fm][j]);
                }
        }
    }
    // reduce over the 16 lanes holding different channels
#pragma unroll
    for (int s = 1; s < 16; s <<= 1)
#pragma unroll
        for (int fm = 0; fm < 2; ++fm)
#pragma unroll
            for (int j = 0; j < 4; ++j) {
                pu0[fm][j] += __shfl_xor(pu0[fm][j], s, 64);
                pu1[fm][j] += __shfl_xor(pu1[fm][j], s, 64);
            }
    if (l15 == 0) {
#pragma unroll
        for (int fm = 0; fm < 2; ++fm)
#pragma unroll
            for (int j = 0; j < 4; ++j) {
                int mrow = wm * 32 + fm * 16 + lg * 4 + j;
                atomicAdd(&sA.ur[mrow][0], pu0[fm][j]);   // 2 N-waves combine
                atomicAdd(&sA.ur[mrow][1], pu1[fm][j]);
            }
    }
    __syncthreads();
    if (tid < BM * 2) {
        int r = tid >> 1, comp = tid & 1;
        u[(gm0 + r) * 2 + comp] = sA.ur[r][comp];
    }
}

// ---------------------------------------------------------------------------
// Finalize: per p, class-sum u over g, result = (su + u)*inv + bc
// ---------------------------------------------------------------------------
__global__ void finalize_kernel(const float* __restrict__ u, const int* __restrict__ y_g,
                                const float* __restrict__ inv, const float* __restrict__ bc,
                                float* __restrict__ out)
{
    int p = blockIdx.x;
    int tid = threadIdx.x;  // 256
    __shared__ float su[NUM_IDS][2];
    if (tid < NUM_IDS * 2) su[tid >> 1][tid & 1] = 0.f;
    __syncthreads();
    for (int h = tid; h < G_DIM; h += 256) {
        int k = y_g[h];
        const float* up = u + ((size_t)p * G_DIM + h) * 2;
        atomicAdd(&su[k][0], up[0]);
        atomicAdd(&su[k][1], up[1]);
    }
    __syncthreads();
    float bc0 = bc[0], bc1 = bc[1];
    for (int h = tid; h < G_DIM; h += 256) {
        int k = y_g[h];
        float iv = inv[k];
        size_t r = (size_t)p * G_DIM + h;
        out[r * 2 + 0] = (su[k][0] + u[r * 2 + 0]) * iv + bc0;
        out[r * 2 + 1] = (su[k][1] + u[r * 2 + 1]) * iv + bc1;
    }
}

__global__ void label_kernel(const int* __restrict__ y_p, const int* __restrict__ y_g,
                             float* __restrict__ outF, long long* __restrict__ outL, int mode)
{
    int i = blockIdx.x * 256 + threadIdx.x;
    if (i >= LABEL_ELEMS) return;
    int p = i >> 10;
    int g = i & 1023;
    long long lab = (y_p[p] == y_g[g]) ? 1 : 0;
    if (mode == 1) outF[i] = (float)lab;
    else           outL[i] = lab;
}

// ---------------------------------------------------------------------------
extern "C" void kernel_launch(void* const* d_in, const int* in_sizes, int n_in,
                              void* d_out, int out_size, void* d_ws, size_t ws_size,
                              hipStream_t stream) {
    const float* d   = (const float*)d_in[0];
    const int*   y_p = (const int*)d_in[1];
    const int*   y_g = (const int*)d_in[2];
    const float* W1  = (const float*)d_in[3];
    const float* b1  = (const float*)d_in[4];
    const float* g1  = (const float*)d_in[5];
    const float* be1 = (const float*)d_in[6];
    const float* rm1 = (const float*)d_in[7];
    const float* rv1 = (const float*)d_in[8];
    const float* W2  = (const float*)d_in[9];
    const float* b2  = (const float*)d_in[10];
    const float* g2  = (const float*)d_in[11];
    const float* be2 = (const float*)d_in[12];
    const float* rm2 = (const float*)d_in[13];
    const float* rv2 = (const float*)d_in[14];
    const float* Wc  = (const float*)d_in[15];
    const float* bc  = (const float*)d_in[16];

    float* ws     = (float*)d_ws;
    float* u      = ws;                       // 262144
    float* alpha1 = u + RESULT_ELEMS;         // 512
    float* beta1  = alpha1 + C_DIM;
    float* alpha2 = beta1 + C_DIM;
    float* beta2  = alpha2 + C_DIM;
    float* inv    = beta2 + C_DIM;            // 64
    bf16*  W1T    = (bf16*)(inv + NUM_IDS);   // 262144 bf16
    bf16*  W2T    = W1T + C_DIM * C_DIM;

    prep_kernel<<<1, 512, 0, stream>>>(b1, g1, be1, rm1, rv1, b2, g2, be2, rm2, rv2,
                                       y_g, alpha1, beta1, alpha2, beta2, inv);

    dim3 tgrid(C_DIM / 64, C_DIM / 64);  // (8,8)
    transpose_scale<<<tgrid, 256, 0, stream>>>(W1, alpha1, W1T);
    transpose_scale<<<tgrid, 256, 0, stream>>>(W2, alpha2, W2T);

    fused_gnn<<<M_DIM / BM, 256, 0, stream>>>(d, W1T, beta1, W2T, beta2, Wc, u);

    float* outF = (float*)d_out;
    finalize_kernel<<<P_DIM, 256, 0, stream>>>(u, y_g, inv, bc, outF);

    int mode = 0;
    if (out_size >= RESULT_ELEMS + 2 * LABEL_ELEMS) mode = 2;
    else if (out_size >= RESULT_ELEMS + LABEL_ELEMS) mode = 1;
    if (mode)
        label_kernel<<<(LABEL_ELEMS + 255) / 256, 256, 0, stream>>>(
            y_p, y_g, outF + RESULT_ELEMS, (long long*)(outF + RESULT_ELEMS), mode);
}

// Round 5
// 662.527 us; speedup vs baseline: 2.9205x; 1.1038x over previous
//
#include <hip/hip_runtime.h>
#include <hip/hip_bf16.h>

#define P_DIM 128
#define G_DIM 1024
#define C_DIM 512
#define M_DIM (P_DIM * G_DIM)       // 131072
#define NUM_IDS 64
#define RESULT_ELEMS (M_DIM * 2)    // 262144
#define LABEL_ELEMS  (M_DIM)        // 131072

typedef __bf16 bf16;
typedef __bf16 bf16x8 __attribute__((ext_vector_type(8)));
typedef float f32x4 __attribute__((ext_vector_type(4)));

__device__ __forceinline__ void gload_lds16(const bf16* g, bf16* l) {
    __builtin_amdgcn_global_load_lds(
        (const __attribute__((address_space(1))) void*)g,
        (__attribute__((address_space(3))) void*)l, 16, 0, 0);
}

// ---------------------------------------------------------------------------
// Prep: beta (BN fold), per-class 1/(n_k+1)
// ---------------------------------------------------------------------------
__global__ void prep_kernel(const float* __restrict__ b1, const float* __restrict__ g1,
                            const float* __restrict__ be1, const float* __restrict__ rm1,
                            const float* __restrict__ rv1,
                            const float* __restrict__ b2, const float* __restrict__ g2,
                            const float* __restrict__ be2, const float* __restrict__ rm2,
                            const float* __restrict__ rv2,
                            const int* __restrict__ y_g,
                            float* __restrict__ beta1, float* __restrict__ beta2,
                            float* __restrict__ inv)
{
    __shared__ int cnt[NUM_IDS];
    int tid = threadIdx.x;  // 512
    if (tid < NUM_IDS) cnt[tid] = 0;
    __syncthreads();
    if (tid < C_DIM) {
        float s1 = g1[tid] * rsqrtf(rv1[tid] + 1e-5f);
        beta1[tid] = (b1[tid] - rm1[tid]) * s1 + be1[tid];
        float s2 = g2[tid] * rsqrtf(rv2[tid] + 1e-5f);
        beta2[tid] = (b2[tid] - rm2[tid]) * s2 + be2[tid];
    }
    for (int h = tid; h < G_DIM; h += 512) atomicAdd(&cnt[y_g[h]], 1);
    __syncthreads();
    if (tid < NUM_IDS) inv[tid] = 1.0f / (float)(cnt[tid] + 1);
}

// ---------------------------------------------------------------------------
// WT[n][k] = W[k][n] * (g[n]*rsqrt(rv[n]+eps)), f32 -> bf16. grid (8,8,2)
// ---------------------------------------------------------------------------
__global__ __launch_bounds__(256) void wprep(
    const float* __restrict__ W1, const float* __restrict__ g1, const float* __restrict__ rv1,
    bf16* __restrict__ W1T,
    const float* __restrict__ W2, const float* __restrict__ g2, const float* __restrict__ rv2,
    bf16* __restrict__ W2T)
{
    const float* W = blockIdx.z ? W2 : W1;
    const float* g = blockIdx.z ? g2 : g1;
    const float* rv = blockIdx.z ? rv2 : rv1;
    bf16* WT = blockIdx.z ? W2T : W1T;

    __shared__ float tile[64][65];
    const int k0 = blockIdx.x * 64, n0 = blockIdx.y * 64;
    const int t = threadIdx.x;
    const int c = t & 63, r4 = t >> 6;
#pragma unroll
    for (int it = 0; it < 16; ++it) {
        int k = r4 + it * 4;
        tile[k][c] = W[(size_t)(k0 + k) * C_DIM + n0 + c];
    }
    __syncthreads();
#pragma unroll
    for (int it = 0; it < 16; ++it) {
        int n = r4 + it * 4;
        float sv = g[n0 + n] * rsqrtf(rv[n0 + n] + 1e-5f);
        WT[(size_t)(n0 + n) * C_DIM + k0 + c] = (bf16)(tile[c][n] * sv);
    }
}

// ---------------------------------------------------------------------------
// d (f32) -> dbf (bf16), 16 elems/thread
// ---------------------------------------------------------------------------
__global__ __launch_bounds__(256) void convert_bf16(const float* __restrict__ x,
                                                    bf16* __restrict__ y)
{
    size_t i = ((size_t)blockIdx.x * 256 + threadIdx.x) * 16;
    float4 a = *(const float4*)(x + i);
    float4 b = *(const float4*)(x + i + 4);
    float4 c = *(const float4*)(x + i + 8);
    float4 e = *(const float4*)(x + i + 12);
    bf16x8 v0, v1;
    v0[0]=(bf16)a.x; v0[1]=(bf16)a.y; v0[2]=(bf16)a.z; v0[3]=(bf16)a.w;
    v0[4]=(bf16)b.x; v0[5]=(bf16)b.y; v0[6]=(bf16)b.z; v0[7]=(bf16)b.w;
    v1[0]=(bf16)c.x; v1[1]=(bf16)c.y; v1[2]=(bf16)c.z; v1[3]=(bf16)c.w;
    v1[4]=(bf16)e.x; v1[5]=(bf16)e.y; v1[6]=(bf16)e.z; v1[7]=(bf16)e.w;
    *(bf16x8*)(y + i) = v0;
    *(bf16x8*)(y + i + 8) = v1;
}

// ---------------------------------------------------------------------------
// m97-style bf16 GEMM, A[M][512] bf16 K-contig, B=WT[N=512][512] bf16 K-contig.
// 128x128 tile, BK=64, 4 waves (2Mx2N), wave 64x64 = 4x4 frags 16x16x32.
// global_load_lds(16B) with inverse-swizzled source; XOR-swizzled ds_read.
// MODE 1: Cout = bf16(lrelu(Z + beta))
// MODE 2: v = lrelu(Z + beta); u[row,:] += v @ Wc   (global atomics)
// ---------------------------------------------------------------------------
template <int MODE>
__global__ __launch_bounds__(256, 4) void gemm_bt(
    const bf16* __restrict__ A, const bf16* __restrict__ B,
    const float* __restrict__ beta, const float* __restrict__ Wc,
    bf16* __restrict__ Cout, float* __restrict__ u)
{
    __shared__ bf16 As[128 * 64];   // 16 KB, row pitch 64 elems (128 B)
    __shared__ bf16 Bs[128 * 64];   // 16 KB

    // XCD-chunked swizzle: grid = 4096 = 4(N) x 1024(M); same-A blocks -> same XCD
    const int orig = blockIdx.x;
    const int wg = (orig & 7) * 512 + (orig >> 3);
    const int bx = wg & 3;
    const int by = wg >> 2;
    const size_t m0 = (size_t)by * 128;
    const int n0 = bx * 128;

    const int tid = threadIdx.x;
    const int ln  = tid & 63;
    const int w   = tid >> 6;
    const int wm  = w & 1;
    const int wn  = w >> 1;
    const int l15 = ln & 15;
    const int lg  = ln >> 4;

    // staging source (inverse swizzle): lane covers (row8 = ln>>3, slot = ln&7),
    // reads global k-slot (slot ^ row8)
    const int srow = ln >> 3;
    const int sw   = (ln & 7) ^ srow;
    const bf16* Ab = A + (m0 + srow) * C_DIM + sw * 8;
    const bf16* Bb = B + (size_t)(n0 + srow) * C_DIM + sw * 8;

    f32x4 acc[4][4];
#pragma unroll
    for (int i = 0; i < 4; ++i)
#pragma unroll
        for (int j = 0; j < 4; ++j) acc[i][j] = (f32x4){0.f, 0.f, 0.f, 0.f};

    for (int k0 = 0; k0 < C_DIM; k0 += 64) {
        __syncthreads();                          // prev tile fully consumed
#pragma unroll
        for (int i = 0; i < 4; ++i) {
            int c = w * 4 + i;                    // chunk: 8 rows, 1024 B
            gload_lds16(Ab + (size_t)c * 8 * C_DIM + k0, &As[c * 512]);
            gload_lds16(Bb + (size_t)c * 8 * C_DIM + k0, &Bs[c * 512]);
        }
        __syncthreads();                          // vmcnt(0) drain -> tile ready
#pragma unroll
        for (int ks = 0; ks < 2; ++ks) {
            bf16x8 af[4], bfr[4];
#pragma unroll
            for (int fm = 0; fm < 4; ++fm) {
                int row = wm * 64 + fm * 16 + l15;
                int slot = (ks * 4 + lg) ^ (l15 & 7);
                af[fm] = *(const bf16x8*)&As[row * 64 + slot * 8];
            }
#pragma unroll
            for (int fn = 0; fn < 4; ++fn) {
                int row = wn * 64 + fn * 16 + l15;
                int slot = (ks * 4 + lg) ^ (l15 & 7);
                bfr[fn] = *(const bf16x8*)&Bs[row * 64 + slot * 8];
            }
#pragma unroll
            for (int fm = 0; fm < 4; ++fm)
#pragma unroll
                for (int fn = 0; fn < 4; ++fn)
                    acc[fm][fn] = __builtin_amdgcn_mfma_f32_16x16x32_bf16(
                        af[fm], bfr[fn], acc[fm][fn], 0, 0, 0);
        }
    }

    if (MODE == 1) {
#pragma unroll
        for (int fn = 0; fn < 4; ++fn) {
            int c = n0 + wn * 64 + fn * 16 + l15;
            float be = beta[c];
#pragma unroll
            for (int fm = 0; fm < 4; ++fm) {
                size_t row = m0 + wm * 64 + fm * 16 + lg * 4;
#pragma unroll
                for (int j = 0; j < 4; ++j) {
                    float v = acc[fm][fn][j] + be;
                    v = v >= 0.f ? v : 0.1f * v;
                    Cout[(row + j) * C_DIM + c] = (bf16)v;
                }
            }
        }
    } else {
        float pu0[4][4] = {}, pu1[4][4] = {};
#pragma unroll
        for (int fn = 0; fn < 4; ++fn) {
            int c = n0 + wn * 64 + fn * 16 + l15;
            float be = beta[c];
            float w0 = Wc[2 * c], w1 = Wc[2 * c + 1];
#pragma unroll
            for (int fm = 0; fm < 4; ++fm)
#pragma unroll
                for (int j = 0; j < 4; ++j) {
                    float v = acc[fm][fn][j] + be;
                    v = v >= 0.f ? v : 0.1f * v;
                    pu0[fm][j] = fmaf(v, w0, pu0[fm][j]);
                    pu1[fm][j] = fmaf(v, w1, pu1[fm][j]);
                }
        }
#pragma unroll
        for (int s = 1; s < 16; s <<= 1)
#pragma unroll
            for (int fm = 0; fm < 4; ++fm)
#pragma unroll
                for (int j = 0; j < 4; ++j) {
                    pu0[fm][j] += __shfl_xor(pu0[fm][j], s, 64);
                    pu1[fm][j] += __shfl_xor(pu1[fm][j], s, 64);
                }
        if (l15 == 0) {
#pragma unroll
            for (int fm = 0; fm < 4; ++fm)
#pragma unroll
                for (int j = 0; j < 4; ++j) {
                    size_t row = m0 + wm * 64 + fm * 16 + lg * 4 + j;
                    atomicAdd(&u[row * 2 + 0], pu0[fm][j]);
                    atomicAdd(&u[row * 2 + 1], pu1[fm][j]);
                }
        }
    }
}

// ---------------------------------------------------------------------------
// Finalize (+label): per p, class-sum u over g; result = (su+u)*inv + bc.
// u ALIASES out[0..RESULT_ELEMS): each thread reads its u value before
// overwriting the same address (pass-1 reads are barrier-separated).
// ---------------------------------------------------------------------------
__global__ void finalize_kernel(const float* __restrict__ u, const int* __restrict__ y_p,
                                const int* __restrict__ y_g,
                                const float* __restrict__ inv, const float* __restrict__ bc,
                                float* __restrict__ out, int mode)
{
    int p = blockIdx.x;
    int tid = threadIdx.x;  // 256
    __shared__ float su[NUM_IDS][2];
    if (tid < NUM_IDS * 2) su[tid >> 1][tid & 1] = 0.f;
    __syncthreads();
    for (int h = tid; h < G_DIM; h += 256) {
        int k = y_g[h];
        const float* up = u + ((size_t)p * G_DIM + h) * 2;
        atomicAdd(&su[k][0], up[0]);
        atomicAdd(&su[k][1], up[1]);
    }
    __syncthreads();
    float bc0 = bc[0], bc1 = bc[1];
    int yp = y_p[p];
    float* outF2 = out + RESULT_ELEMS;
    long long* outL = (long long*)(out + RESULT_ELEMS);
    for (int h = tid; h < G_DIM; h += 256) {
        int k = y_g[h];
        float iv = inv[k];
        size_t r = (size_t)p * G_DIM + h;
        float u0 = u[r * 2 + 0], u1 = u[r * 2 + 1];
        out[r * 2 + 0] = (su[k][0] + u0) * iv + bc0;
        out[r * 2 + 1] = (su[k][1] + u1) * iv + bc1;
        if (mode == 2)      outL[r]  = (y_g[h] == yp) ? 1 : 0;
        else if (mode == 1) outF2[r] = (y_g[h] == yp) ? 1.f : 0.f;
    }
}

// ---------------------------------------------------------------------------
extern "C" void kernel_launch(void* const* d_in, const int* in_sizes, int n_in,
                              void* d_out, int out_size, void* d_ws, size_t ws_size,
                              hipStream_t stream) {
    const float* d   = (const float*)d_in[0];
    const int*   y_p = (const int*)d_in[1];
    const int*   y_g = (const int*)d_in[2];
    const float* W1  = (const float*)d_in[3];
    const float* b1  = (const float*)d_in[4];
    const float* g1  = (const float*)d_in[5];
    const float* be1 = (const float*)d_in[6];
    const float* rm1 = (const float*)d_in[7];
    const float* rv1 = (const float*)d_in[8];
    const float* W2  = (const float*)d_in[9];
    const float* b2  = (const float*)d_in[10];
    const float* g2  = (const float*)d_in[11];
    const float* be2 = (const float*)d_in[12];
    const float* rm2 = (const float*)d_in[13];
    const float* rv2 = (const float*)d_in[14];
    const float* Wc  = (const float*)d_in[15];
    const float* bc  = (const float*)d_in[16];

    // ws layout — u now lives in d_out; total ws usage 269,488,384 B
    // (<= the 269,496,320 B proven safe by the round-1 passing kernel).
    float* ws    = (float*)d_ws;
    float* beta1 = ws;                        // 512
    float* beta2 = beta1 + C_DIM;             // 512
    float* inv   = beta2 + C_DIM;             // 64
    bf16*  dbf   = (bf16*)(inv + NUM_IDS);    // 67108864 bf16
    bf16*  h1    = dbf + (size_t)M_DIM * C_DIM;
    bf16*  W1T   = h1 + (size_t)M_DIM * C_DIM;
    bf16*  W2T   = W1T + C_DIM * C_DIM;

    float* outF = (float*)d_out;
    float* u    = outF;                       // scratch: overwritten in-place by finalize

    hipMemsetAsync(u, 0, RESULT_ELEMS * sizeof(float), stream);

    prep_kernel<<<1, 512, 0, stream>>>(b1, g1, be1, rm1, rv1, b2, g2, be2, rm2, rv2,
                                       y_g, beta1, beta2, inv);

    dim3 tgrid(C_DIM / 64, C_DIM / 64, 2);
    wprep<<<tgrid, 256, 0, stream>>>(W1, g1, rv1, W1T, W2, g2, rv2, W2T);

    convert_bf16<<<M_DIM * C_DIM / (256 * 16), 256, 0, stream>>>(d, dbf);

    gemm_bt<1><<<4096, 256, 0, stream>>>(dbf, W1T, beta1, nullptr, h1, nullptr);
    gemm_bt<2><<<4096, 256, 0, stream>>>(h1, W2T, beta2, Wc, nullptr, u);

    int mode = 0;
    if (out_size >= RESULT_ELEMS + 2 * LABEL_ELEMS) mode = 2;
    else if (out_size >= RESULT_ELEMS + LABEL_ELEMS) mode = 1;
    finalize_kernel<<<P_DIM, 256, 0, stream>>>(u, y_p, y_g, inv, bc, outF, mode);
}